// Round 9
// baseline (366.756 us; speedup 1.0000x reference)
//
#include <hip/hip_runtime.h>

// MultiHead attention, B=4 L=2048 D=1024 H=16 HD=64.
// R9: (a) qkv_gemm Q/K path: swapped MFMA operands -> C^T fragment -> j runs
// along d -> uint2 epilogue stores (16 vs 64 instrs); (b) gemm_wo same trick,
// float4 stores; (c) attn: row-sum l via ones-MFMA (matrix pipe has headroom)
// instead of 56 VALU adds/tile + shfl epilogue.

#define Bsz 4
#define Lq 2048
#define Dm 1024
#define NH 16
#define HD 64
// 0.125 * log2(e): folded into Wq/bq so attention uses exp2 directly
#define QSCALE 0.18033688011112042f

typedef unsigned short u16;
typedef __attribute__((ext_vector_type(8))) short short8;
typedef __attribute__((ext_vector_type(4))) float f32x4;

#define MFMA32(a, b, c) __builtin_amdgcn_mfma_f32_16x16x32_bf16(a, b, c, 0, 0, 0)

typedef __attribute__((address_space(3))) unsigned su32;
typedef __attribute__((address_space(1))) unsigned gu32;
__device__ __forceinline__ void gl_lds16(const u16* g, u16* l) {
  __builtin_amdgcn_global_load_lds((gu32*)(g), (su32*)(l), 16, 0, 0);
}

__device__ __forceinline__ u16 f2b(float x) {
  unsigned u = __builtin_bit_cast(unsigned, x);
  return (u16)((u + 0x7fffu + ((u >> 16) & 1u)) >> 16);  // RNE
}
__device__ __forceinline__ unsigned pk2(float a, float b) {
  return (unsigned)f2b(a) | ((unsigned)f2b(b) << 16);
}
// round-half-up bf16 pair pack via v_perm: lo=bf16(a), hi=bf16(b)
__device__ __forceinline__ unsigned pk2p(float a, float b) {
  return __builtin_amdgcn_perm(__builtin_bit_cast(unsigned, b) + 0x8000u,
                               __builtin_bit_cast(unsigned, a) + 0x8000u, 0x07060302u);
}
__device__ __forceinline__ float fexp2(float x) {
#if __has_builtin(__builtin_amdgcn_exp2f)
  return __builtin_amdgcn_exp2f(x);
#else
  return exp2f(x);
#endif
}

// ---------------- fused triple activation cast fp32 -> bf16 ----------------
__global__ void castk3(const float* __restrict__ q, const float* __restrict__ k,
                       const float* __restrict__ v, u16* __restrict__ dst) {
  const float* s = blockIdx.y == 0 ? q : (blockIdx.y == 1 ? k : v);
  u16* d = dst + (size_t)blockIdx.y * (Bsz * Lq * Dm);
  int i = (blockIdx.x * 256 + threadIdx.x) * 8;
  float4 a = *(const float4*)(s + i);
  float4 b = *(const float4*)(s + i + 4);
  short8 o;
  o[0] = (short)f2b(a.x); o[1] = (short)f2b(a.y);
  o[2] = (short)f2b(a.z); o[3] = (short)f2b(a.w);
  o[4] = (short)f2b(b.x); o[5] = (short)f2b(b.y);
  o[6] = (short)f2b(b.z); o[7] = (short)f2b(b.w);
  *(short8*)(d + i) = o;
}

// fused 4-weight cast, blockIdx.y selects matrix
__global__ void castw(const float* __restrict__ s0, const float* __restrict__ s1,
                      const float* __restrict__ s2, const float* __restrict__ s3,
                      u16* __restrict__ d0, u16* __restrict__ d1,
                      u16* __restrict__ d2, u16* __restrict__ d3) {
  const float* s; u16* d; float sc = 1.0f;
  switch (blockIdx.y) {
    case 0: s = s0; d = d0; sc = QSCALE; break;
    case 1: s = s1; d = d1; break;
    case 2: s = s2; d = d2; break;
    default: s = s3; d = d3; break;
  }
  int i = (blockIdx.x * 256 + threadIdx.x) * 8;
  float4 a = *(const float4*)(s + i);
  float4 b = *(const float4*)(s + i + 4);
  short8 o;
  o[0] = (short)f2b(a.x * sc); o[1] = (short)f2b(a.y * sc);
  o[2] = (short)f2b(a.z * sc); o[3] = (short)f2b(a.w * sc);
  o[4] = (short)f2b(b.x * sc); o[5] = (short)f2b(b.y * sc);
  o[6] = (short)f2b(b.z * sc); o[7] = (short)f2b(b.w * sc);
  *(short8*)(d + i) = o;
}

// ---------------- fused QKV projection GEMM ----------------
// grid (8, 64, 3). z: {q->Qh (scaled), k->Kh, v->Vtg (transposed+permuted)}.
// z<2 path: swapped MFMA operands -> lane holds fixed l=r16-based row, j runs
// along d -> uint2 stores.
__global__ __launch_bounds__(256) void qkv_gemm(
    const u16* __restrict__ Ab,
    const u16* __restrict__ Wqb, const u16* __restrict__ Wkb, const u16* __restrict__ Wvb,
    const float* __restrict__ bq, const float* __restrict__ bk, const float* __restrict__ bv,
    u16* __restrict__ Qh, u16* __restrict__ Kh, u16* __restrict__ Vtg)
{
  __shared__ __align__(16) u16 As[128 * 32];
  __shared__ __align__(16) u16 Bs[128 * 32];
  const int z = blockIdx.z;
  const u16* A  = Ab + (size_t)z * (Bsz * Lq * Dm);
  const u16* Bt = z == 0 ? Wqb : (z == 1 ? Wkb : Wvb);
  const float* bias = z == 0 ? bq : (z == 1 ? bk : bv);
  const float bscale = z == 0 ? QSCALE : 1.0f;

  const int tid  = threadIdx.x;
  const int lane = tid & 63;
  const int wave = tid >> 6;
  const int quad = lane >> 4;
  const int r16  = lane & 15;
  const int wm   = (wave >> 1) * 64;
  const int wn   = (wave & 1) * 64;
  const int m0   = blockIdx.y * 128;
  const int n0   = blockIdx.x * 128;

  const u16* ga = A  + (size_t)(m0 + wave * 32 + (lane >> 2)) * Dm + (lane & 3) * 8;
  const u16* gb = Bt + (size_t)(n0 + wave * 32 + (lane >> 2)) * Dm + (lane & 3) * 8;
  u16* la = As + wave * 1024;
  u16* lb = Bs + wave * 1024;

  f32x4 acc[4][4] = {};

  if (z < 2) {
    // ---- swapped-operand K-loop: acc = C^T fragments ----
    for (int k0 = 0; k0 < Dm; k0 += 32) {
      gl_lds16(ga + k0, la);
      gl_lds16(ga + k0 + 16 * Dm, la + 512);
      gl_lds16(gb + k0, lb);
      gl_lds16(gb + k0 + 16 * Dm, lb + 512);
      __syncthreads();
      short8 af[4], bfr[4];
#pragma unroll
      for (int mt = 0; mt < 4; ++mt) af[mt]  = *(const short8*)&As[(wm + mt * 16 + r16) * 32 + quad * 8];
#pragma unroll
      for (int nt = 0; nt < 4; ++nt) bfr[nt] = *(const short8*)&Bs[(wn + nt * 16 + r16) * 32 + quad * 8];
#pragma unroll
      for (int mt = 0; mt < 4; ++mt)
#pragma unroll
        for (int nt = 0; nt < 4; ++nt)
          acc[mt][nt] = MFMA32(bfr[nt], af[mt], acc[mt][nt]);  // swapped
      __syncthreads();
    }
    // epilogue: lane holds l = m0+wm+mt*16+r16 (fixed), n = nb+j (j=0..3)
    u16* dst = z == 0 ? Qh : Kh;
#pragma unroll
    for (int nt = 0; nt < 4; ++nt) {
      const int nb = n0 + wn + nt * 16 + quad * 4;
      float4 bv4 = *(const float4*)&bias[nb];
      const int h = nb >> 6, d = nb & 63;
#pragma unroll
      for (int mt = 0; mt < 4; ++mt) {
        const int l = m0 + wm + mt * 16 + r16;
        const int b = l >> 11, lq = l & 2047;
        uint2 pkd;
        pkd.x = pk2(acc[mt][nt][0] + bv4.x * bscale, acc[mt][nt][1] + bv4.y * bscale);
        pkd.y = pk2(acc[mt][nt][2] + bv4.z * bscale, acc[mt][nt][3] + bv4.w * bscale);
        *(uint2*)&dst[(((size_t)(b * NH + h)) * Lq + lq) * HD + d] = pkd;
      }
    }
  } else {
    // ---- V path: normal operand order, transposed+permuted store ----
    for (int k0 = 0; k0 < Dm; k0 += 32) {
      gl_lds16(ga + k0, la);
      gl_lds16(ga + k0 + 16 * Dm, la + 512);
      gl_lds16(gb + k0, lb);
      gl_lds16(gb + k0 + 16 * Dm, lb + 512);
      __syncthreads();
      short8 af[4], bfr[4];
#pragma unroll
      for (int mt = 0; mt < 4; ++mt) af[mt]  = *(const short8*)&As[(wm + mt * 16 + r16) * 32 + quad * 8];
#pragma unroll
      for (int nt = 0; nt < 4; ++nt) bfr[nt] = *(const short8*)&Bs[(wn + nt * 16 + r16) * 32 + quad * 8];
#pragma unroll
      for (int mt = 0; mt < 4; ++mt)
#pragma unroll
        for (int nt = 0; nt < 4; ++nt)
          acc[mt][nt] = MFMA32(af[mt], bfr[nt], acc[mt][nt]);
      __syncthreads();
    }
#pragma unroll
    for (int mt = 0; mt < 4; ++mt) {
#pragma unroll
      for (int nt = 0; nt < 4; ++nt) {
        int n = n0 + wn + nt * 16 + r16;
        float bv_ = bias[n];
        // Vtg[bh][d][l'], l' permuted within 32-block: q<<3|w<<2|j
        int m_base = m0 + wm + mt * 16 + quad * 4;
        int b = m_base >> 11, l0 = m_base & 2047;
        int lp = (l0 & ~31) | (((l0 >> 2) & 3) << 3) | (((l0 >> 4) & 1) << 2);
        int h = n >> 6, d = n & 63;
        u16* dstv = Vtg + (((size_t)(b * NH + h)) * HD + d) * Lq + lp;
        uint2 pkd;
        pkd.x = pk2(acc[mt][nt][0] + bv_, acc[mt][nt][1] + bv_);
        pkd.y = pk2(acc[mt][nt][2] + bv_, acc[mt][nt][3] + bv_);
        *(uint2*)dstv = pkd;
      }
    }
  }
}

// ---------------- Wo GEMM: 128x64 tile, swapped operands, float4 out --------
__global__ __launch_bounds__(256) void gemm_wo(
    const u16* __restrict__ A, const u16* __restrict__ Bt,
    const float* __restrict__ bias, float* __restrict__ C)
{
  __shared__ __align__(16) u16 As[128 * 32];
  __shared__ __align__(16) u16 Bs[64 * 32];
  const int tid  = threadIdx.x;
  const int lane = tid & 63;
  const int wave = tid >> 6;
  const int quad = lane >> 4;
  const int r16  = lane & 15;
  const int wm   = wave * 32;
  const int m0   = blockIdx.y * 128;
  const int n0   = blockIdx.x * 64;

  const u16* ga = A  + (size_t)(m0 + wave * 32 + (lane >> 2)) * Dm + (lane & 3) * 8;
  const u16* gb = Bt + (size_t)(n0 + wave * 16 + (lane >> 2)) * Dm + (lane & 3) * 8;
  u16* la = As + wave * 1024;
  u16* lb = Bs + wave * 512;

  f32x4 acc[2][4] = {};

  for (int k0 = 0; k0 < Dm; k0 += 32) {
    gl_lds16(ga + k0, la);
    gl_lds16(ga + k0 + 16 * Dm, la + 512);
    gl_lds16(gb + k0, lb);
    __syncthreads();

    short8 af[2], bfr[4];
#pragma unroll
    for (int mt = 0; mt < 2; ++mt) af[mt]  = *(const short8*)&As[(wm + mt * 16 + r16) * 32 + quad * 8];
#pragma unroll
    for (int nt = 0; nt < 4; ++nt) bfr[nt] = *(const short8*)&Bs[(nt * 16 + r16) * 32 + quad * 8];
#pragma unroll
    for (int mt = 0; mt < 2; ++mt)
#pragma unroll
      for (int nt = 0; nt < 4; ++nt)
        acc[mt][nt] = MFMA32(bfr[nt], af[mt], acc[mt][nt]);  // swapped
    __syncthreads();
  }

  // epilogue: lane holds m = m0+wm+mt*16+r16 (fixed), n = nb+j -> float4
#pragma unroll
  for (int nt = 0; nt < 4; ++nt) {
    const int nb = n0 + nt * 16 + quad * 4;
    float4 bv4 = *(const float4*)&bias[nb];
#pragma unroll
    for (int mt = 0; mt < 2; ++mt) {
      const int m = m0 + wm + mt * 16 + r16;
      float4 o;
      o.x = acc[mt][nt][0] + bv4.x;
      o.y = acc[mt][nt][1] + bv4.y;
      o.z = acc[mt][nt][2] + bv4.z;
      o.w = acc[mt][nt][3] + bv4.w;
      *(float4*)&C[(size_t)m * Dm + nb] = o;
    }
  }
}

// ---------------- fused flash attention (S^T form, K=32 PV, ones-MFMA l) ----
__global__ __launch_bounds__(256) void attn5(
    const u16* __restrict__ Qh, const u16* __restrict__ Kh,
    const u16* __restrict__ Vtg, u16* __restrict__ Oa)
{
  const int bh = blockIdx.y;   // 0..63
  const int qt = blockIdx.x;   // 0..15
  const int tid = threadIdx.x, lane = tid & 63, wave = tid >> 6;
  const int quad = lane >> 4, r16 = lane & 15;

  __shared__ __align__(16) u16 Ks[64][72];   // [kpos][d]
  __shared__ __align__(16) u16 Vt[64][72];   // [d][kpos'] (permuted cols)

  const int qbase = qt * 128 + wave * 32;
  short8 aq[2][2];
#pragma unroll
  for (int qf = 0; qf < 2; ++qf) {
    const size_t qrow = ((size_t)bh * Lq + qbase + qf * 16 + r16) * HD;
    aq[qf][0] = *(const short8*)(Qh + qrow + quad * 8);
    aq[qf][1] = *(const short8*)(Qh + qrow + 32 + quad * 8);
  }

  f32x4 oacc[2][4] = {};
  f32x4 lacc[2] = {};
  short8 ones8;
#pragma unroll
  for (int i = 0; i < 8; ++i) ones8[i] = (short)0x3F80;  // bf16 1.0

  const int srow = tid >> 2;        // 0..63
  const int scid = (tid & 3) * 16;  // 0,16,32,48
  const u16* kg = Kh  + ((size_t)bh * Lq + srow) * HD + scid;
  const u16* vg = Vtg + ((size_t)bh * HD + srow) * Lq + scid;

  short8 pk0 = *(const short8*)(kg);
  short8 pk1 = *(const short8*)(kg + 8);
  short8 pv0 = *(const short8*)(vg);
  short8 pv1 = *(const short8*)(vg + 8);

  for (int t = 0; t < 32; ++t) {
    __syncthreads();
    *(short8*)&Ks[srow][scid]     = pk0;
    *(short8*)&Ks[srow][scid + 8] = pk1;
    *(short8*)&Vt[srow][scid]     = pv0;
    *(short8*)&Vt[srow][scid + 8] = pv1;
    __syncthreads();
    if (t < 31) {
      const u16* kgn = kg + (size_t)(t + 1) * 64 * HD;
      const u16* vgn = vg + (t + 1) * 64;
      pk0 = *(const short8*)(kgn);
      pk1 = *(const short8*)(kgn + 8);
      pv0 = *(const short8*)(vgn);
      pv1 = *(const short8*)(vgn + 8);
    }

#pragma unroll
    for (int ks = 0; ks < 2; ++ks) {
      f32x4 stq[2][2];
#pragma unroll
      for (int mtl = 0; mtl < 2; ++mtl) {
        const int mt = 2 * ks + mtl;
        short8 kf0 = *(const short8*)&Ks[mt * 16 + r16][quad * 8];
        short8 kf1 = *(const short8*)&Ks[mt * 16 + r16][32 + quad * 8];
#pragma unroll
        for (int qf = 0; qf < 2; ++qf) {
          f32x4 zz = {};
          zz = MFMA32(kf0, aq[qf][0], zz);
          zz = MFMA32(kf1, aq[qf][1], zz);
          stq[qf][mtl] = zz;
        }
      }
      short8 vf[4];
#pragma unroll
      for (int nt = 0; nt < 4; ++nt)
        vf[nt] = *(const short8*)&Vt[nt * 16 + r16][ks * 32 + quad * 8];
#pragma unroll
      for (int qf = 0; qf < 2; ++qf) {
        f32x4 sa = stq[qf][0], sb = stq[qf][1];
        float p0 = fexp2(sa[0]), p1 = fexp2(sa[1]), p2 = fexp2(sa[2]), p3 = fexp2(sa[3]);
        float p4 = fexp2(sb[0]), p5 = fexp2(sb[1]), p6 = fexp2(sb[2]), p7 = fexp2(sb[3]);
        uint4 pu;
        pu.x = pk2p(p0, p1);
        pu.y = pk2p(p2, p3);
        pu.z = pk2p(p4, p5);
        pu.w = pk2p(p6, p7);
        short8 pb = __builtin_bit_cast(short8, pu);
        lacc[qf] = MFMA32(ones8, pb, lacc[qf]);   // row-sum of P via matrix pipe
#pragma unroll
        for (int nt = 0; nt < 4; ++nt)
          oacc[qf][nt] = MFMA32(vf[nt], pb, oacc[qf][nt]);
      }
    }
  }

  const int b = bh >> 4, h = bh & 15;
#pragma unroll
  for (int qf = 0; qf < 2; ++qf) {
    float linv = 1.0f / lacc[qf][0];   // all rows of lacc hold l for q=r16
    int q = qbase + qf * 16 + r16;
    size_t rowb = ((size_t)(b * Lq + q)) * Dm + h * HD;
#pragma unroll
    for (int nt = 0; nt < 4; ++nt) {
      f32x4 o = oacc[qf][nt];
      uint2 pkd;
      pkd.x = pk2(o[0] * linv, o[1] * linv);
      pkd.y = pk2(o[2] * linv, o[3] * linv);
      *(uint2*)&Oa[rowb + nt * 16 + quad * 4] = pkd;
    }
  }
}

// ---------------- launcher ----------------
extern "C" void kernel_launch(void* const* d_in, const int* in_sizes, int n_in,
                              void* d_out, int out_size, void* d_ws, size_t ws_size,
                              hipStream_t stream) {
  const float* q  = (const float*)d_in[0];
  const float* k  = (const float*)d_in[1];
  const float* v  = (const float*)d_in[2];
  const float* Wq = (const float*)d_in[3];
  const float* bq = (const float*)d_in[4];
  const float* Wk = (const float*)d_in[5];
  const float* bk = (const float*)d_in[6];
  const float* Wv = (const float*)d_in[7];
  const float* bv = (const float*)d_in[8];
  const float* Wo = (const float*)d_in[9];
  const float* bo = (const float*)d_in[10];

  const int NA = Bsz * Lq * Dm;  // 8388608
  u16* abuf = (u16*)d_ws;            // [3][M][K] activations bf16; later Oa
  u16* Qh   = abuf + (size_t)3 * NA;
  u16* Kh   = Qh   + NA;
  u16* Vtg  = Kh   + NA;
  u16* wqb  = Vtg  + NA;
  u16* wkb  = wqb  + 1048576;
  u16* wvb  = wkb  + 1048576;
  u16* wob  = wvb  + 1048576;

  castw<<<dim3(512, 4), 256, 0, stream>>>(Wq, Wk, Wv, Wo, wqb, wkb, wvb, wob);
  castk3<<<dim3(NA / 2048, 3), 256, 0, stream>>>(q, k, v, abuf);

  qkv_gemm<<<dim3(8, 64, 3), 256, 0, stream>>>(abuf, wqb, wkb, wvb, bq, bk, bv, Qh, Kh, Vtg);

  attn5<<<dim3(Lq / 128, Bsz * NH), 256, 0, stream>>>(Qh, Kh, Vtg, abuf);

  gemm_wo<<<dim3(16, 64), 256, 0, stream>>>(abuf, wob, bo, (float*)d_out);
}